// Round 18
// baseline (90.789 us; speedup 1.0000x reference)
//
#include <hip/hip_runtime.h>
#include <cstdint>
#include <cstddef>

typedef __bf16 bf16x8 __attribute__((ext_vector_type(8)));
typedef float f32x4 __attribute__((ext_vector_type(4)));
typedef unsigned int u32x4 __attribute__((ext_vector_type(4)));
typedef unsigned short u16;
typedef unsigned short u16x8 __attribute__((ext_vector_type(8)));

__device__ __forceinline__ u16 f2b(float f) {
    union { float f; uint32_t u; } v; v.f = f;
    uint32_t r = v.u + 0x7fffu + ((v.u >> 16) & 1u);
    return (u16)(r >> 16);
}
__device__ __forceinline__ float b2f(u16 h) {
    union { uint32_t u; float f; } v; v.u = ((uint32_t)h) << 16; return v.f;
}

// ---------------- kernel 1: prep = weight bf16 converts + time conditioning
__global__ __launch_bounds__(256) void prep_kernel(
    const float* __restrict__ Wq, const float* __restrict__ Wkv, const float* __restrict__ Wo,
    const float* __restrict__ timep, const float* __restrict__ Wt, const float* __restrict__ bt,
    u16* __restrict__ wqkv, u16* __restrict__ wo, float* __restrict__ tbuf)
{
    __shared__ float st[512];
    int bx = blockIdx.x, tid = threadIdx.x;
    if (bx < 1024) {
        int i = bx * 256 + tid;
        float4 v; u16* dp;
        if (i < 65536)      { v = ((const float4*)Wq)[i];            dp = wqkv + (size_t)i * 4; }
        else if (i < 196608){ int k = i - 65536;  v = ((const float4*)Wkv)[k]; dp = wqkv + 262144 + (size_t)k * 4; }
        else                { int k = i - 196608; v = ((const float4*)Wo)[k];  dp = wo + (size_t)k * 4; }
        ushort4 o;
        o.x = f2b(v.x); o.y = f2b(v.y); o.z = f2b(v.z); o.w = f2b(v.w);
        *(ushort4*)dp = o;
    } else {
        int bx2 = bx - 1024;          // 8 blocks
        int b = bx2 >> 2, ch = bx2 & 3;
        for (int k = tid; k < 512; k += 256) {
            float v = timep[b * 512 + k];
            st[k] = v / (1.f + __expf(-v));
        }
        __syncthreads();
        int o = ch * 256 + tid;
        const float4* wrow = (const float4*)(Wt + (size_t)o * 512);
        float acc = bt[o];
        #pragma unroll 4
        for (int k4 = 0; k4 < 128; k4++) {
            float4 w = wrow[k4];
            acc += st[k4*4+0]*w.x + st[k4*4+1]*w.y + st[k4*4+2]*w.z + st[k4*4+3]*w.w;
        }
        tbuf[b * 1024 + o] = acc;
    }
}

// ---------------- kernel 2: LayerNorm + (scale+1)*x + shift, * mask -> xn bf16
__global__ __launch_bounds__(64) void ln_cond_kernel(
    const float* __restrict__ x, const float* __restrict__ gamma,
    const float* __restrict__ tbuf, const float* __restrict__ seq_mask,
    u16* __restrict__ xn)
{
    int m = blockIdx.x;              // 0..2047  (b*1024+n)
    int b = m >> 10;
    int lane = threadIdx.x;
    const float* xr = x + (size_t)m * 512;
    int c0 = lane * 8;
    float4 v0 = *(const float4*)(xr + c0);
    float4 v1 = *(const float4*)(xr + c0 + 4);
    float xv[8] = {v0.x, v0.y, v0.z, v0.w, v1.x, v1.y, v1.z, v1.w};
    float s = 0.f, ss = 0.f;
    #pragma unroll
    for (int e = 0; e < 8; e++) { s += xv[e]; ss += xv[e]*xv[e]; }
    #pragma unroll
    for (int off = 1; off < 64; off <<= 1) {
        s  += __shfl_xor(s, off);
        ss += __shfl_xor(ss, off);
    }
    float mu = s * (1.f/512.f);
    float var = ss * (1.f/512.f) - mu*mu;
    float rs = rsqrtf(var + 1e-5f);
    float mk = seq_mask[m];
    u16x8 ov;
    #pragma unroll
    for (int e = 0; e < 8; e++) {
        int c = c0 + e;
        float sc = tbuf[b*1024 + c] + 1.f;
        float sh = tbuf[b*1024 + 512 + c];
        float val = ((xv[e] - mu) * rs * gamma[c] * sc + sh) * mk;
        ov[e] = f2b(val);
    }
    *(u16x8*)&xn[(size_t)m * 512 + c0] = ov;
}

// ---------------- kernel 3: fused [bias (blocks 0..2047, FIRST)] + [QKV GEMM 64^2 (2048..2815)]
// Single change vs R17: dispatch order flipped (bodies identical).
#define TST 68
__global__ __launch_bounds__(256, 8) void qkv_bias_kernel(
    const float* __restrict__ ab, const float* __restrict__ Wb, const float* __restrict__ bbv,
    const u16* __restrict__ xn, const u16* __restrict__ wqkv,
    u16* __restrict__ bias_t, u16* __restrict__ qb, u16* __restrict__ kb, u16* __restrict__ vT)
{
    __shared__ u16 SH[8704];         // bias: Ts[8*16*68]=17408B; GEMM: As[64][40]+Bs[64][40]=10240B
    __shared__ float wbs[128];
    __shared__ float bbs[8];
    const int tid = threadIdx.x;
    const int bx = blockIdx.x;
    if (bx < 2048) {
        // ---- bias path (dispatched first) ----
        if (tid < 128) wbs[tid] = Wb[tid];
        if (tid < 8) bbs[tid] = bbv[tid];
        __syncthreads();
        int bx2 = bx;                   // 0..2047
        int b = bx2 >> 10;
        int rem = bx2 & 1023;
        int i16 = rem >> 4;             // 16-row group
        int jt  = rem & 15;
        int il = tid >> 4, jq = tid & 15;
        int i = i16*16 + il;
        int j = jt*64 + jq*4;
        const float* base = ab + (((size_t)b << 24)) + ((size_t)i << 10) + j;

        int a0 = bx2 & 15;              // staggered plane start (channel spread)
        f32x4 acc[8];
        #pragma unroll
        for (int h = 0; h < 8; h++) {
            float bv = bbs[h];
            acc[h][0] = bv; acc[h][1] = bv; acc[h][2] = bv; acc[h][3] = bv;
        }
        f32x4 v[16];
        #pragma unroll
        for (int k = 0; k < 16; k++) {
            int a = (a0 + k) & 15;
            v[k] = *(const f32x4*)(base + ((size_t)a << 20));
        }
        #pragma unroll
        for (int k = 0; k < 16; k++) {
            int a = (a0 + k) & 15;
            #pragma unroll
            for (int h = 0; h < 8; h++)
                acc[h] += wbs[h*16 + a] * v[k];
        }
        // to LDS (bf16), layout [h][il][j-local], stride TST
        #pragma unroll
        for (int h = 0; h < 8; h++) {
            ushort4 o;
            o.x = f2b(acc[h][0]); o.y = f2b(acc[h][1]); o.z = f2b(acc[h][2]); o.w = f2b(acc[h][3]);
            *(ushort4*)&SH[(h*16 + il)*TST + jq*4] = o;
        }
        __syncthreads();
        // frag-order read + contiguous store
        int hh = tid >> 5;
        int s0 = tid & 31;
        size_t tilebase = ((((size_t)(b*8 + hh))*32 + (i16 >> 1))*16 + jt)*2048 + (size_t)(i16 & 1)*1024;
        #pragma unroll
        for (int ss = 0; ss < 2; ss++) {
            int slot = s0 + ss*32;
            int g = slot >> 4, li = slot & 15;
            u16 tmp[16];
            #pragma unroll
            for (int r = 0; r < 4; r++)
                #pragma unroll
                for (int fj = 0; fj < 4; fj++)
                    tmp[r*4 + fj] = SH[(hh*16 + g*4 + r)*TST + fj*16 + li];
            *(uint4*)&bias_t[tilebase + (size_t)slot*16]     = *(uint4*)&tmp[0];
            *(uint4*)&bias_t[tilebase + (size_t)slot*16 + 8] = *(uint4*)&tmp[8];
        }
    } else {
        // ---- qkv GEMM path, 64x64 tile (low VGPR) ----
        u16 (*As)[40] = (u16(*)[40])&SH[0];
        u16 (*Bs)[40] = (u16(*)[40])&SH[2560];
        int v = bx - 2048;           // 0..767: 32 m-tiles x 24 n-tiles
        const int m0 = (v & 31) * 64, n0 = (v >> 5) * 64;
        const int lane = tid & 63, wid = tid >> 6;
        const int wr = wid >> 1, wc = wid & 1;
        const int li = lane & 15, g = lane >> 4;
        f32x4 acc[2][2] = {};
        const int lrow = tid >> 2, lcol = (tid & 3) * 8;
        for (int k0 = 0; k0 < 512; k0 += 32) {
            *(bf16x8*)&As[lrow][lcol] = *(const bf16x8*)&xn[(size_t)(m0+lrow)*512 + k0 + lcol];
            *(bf16x8*)&Bs[lrow][lcol] = *(const bf16x8*)&wqkv[(size_t)(n0+lrow)*512 + k0 + lcol];
            __syncthreads();
            bf16x8 a[2], bf[2];
            #pragma unroll
            for (int fi = 0; fi < 2; fi++) a[fi]  = *(const bf16x8*)&As[wr*32 + fi*16 + li][g*8];
            #pragma unroll
            for (int fj = 0; fj < 2; fj++) bf[fj] = *(const bf16x8*)&Bs[wc*32 + fj*16 + li][g*8];
            #pragma unroll
            for (int fi = 0; fi < 2; fi++)
                #pragma unroll
                for (int fj = 0; fj < 2; fj++)
                    acc[fi][fj] = __builtin_amdgcn_mfma_f32_16x16x32_bf16(a[fi], bf[fj], acc[fi][fj], 0, 0, 0);
            __syncthreads();
        }
        #pragma unroll
        for (int fi = 0; fi < 2; fi++)
            #pragma unroll
            for (int fj = 0; fj < 2; fj++) {
                int o = n0 + wc*32 + fj*16 + li;
                int m_base = m0 + wr*32 + fi*16 + g*4;
                if (o < 1024) {
                    #pragma unroll
                    for (int r = 0; r < 4; r++) {
                        int m = m_base + r;
                        int b = m >> 10, n = m & 1023;
                        float vv = acc[fi][fj][r];
                        if (o < 512) {
                            qb[((size_t)(b*8 + (o>>6))*1024 + n)*64 + (o&63)] = f2b(vv * 0.125f);
                        } else {
                            int oo = o - 512;
                            kb[((size_t)(b*8 + (oo>>6))*1024 + n)*64 + (oo&63)] = f2b(vv);
                        }
                    }
                } else {
                    int oo = o - 1024;
                    int b = m_base >> 10, n = m_base & 1023;
                    ushort4 ov;
                    ov.x = f2b(acc[fi][fj][0]); ov.y = f2b(acc[fi][fj][1]);
                    ov.z = f2b(acc[fi][fj][2]); ov.w = f2b(acc[fi][fj][3]);
                    *(ushort4*)&vT[((size_t)(b*8 + (oo>>6))*64 + (oo&63))*1024 + n] = ov;
                }
            }
    }
}

// ---------------- kernel 4: flash attention, lane-linear LDS slots, j-split x2 (R8 exact)
__global__ __launch_bounds__(256) void attn_kernel(
    const u16* __restrict__ qb, const u16* __restrict__ kb, const u16* __restrict__ vT,
    const u16* __restrict__ bias_t, const float* __restrict__ seq_mask,
    float* __restrict__ Om, float* __restrict__ ml)
{
    __shared__ u16 Ks[2][4096];
    __shared__ u16 Vs[2][4096];
    __shared__ u16 Ps[4][1024];
    __shared__ float mjs[512];
    int tid = threadIdx.x;
    int lane = tid & 63, w = tid >> 6;
    int li = lane & 15, g = lane >> 4;
    int it = blockIdx.x, h = blockIdx.y;
    int bz = blockIdx.z;
    int b = bz >> 1, jh = bz & 1;
    int bh = b*8 + h;
    int i0 = it * 64;
    int jt0 = jh * 8;
    const u16* qp = qb + ((size_t)bh*1024 + i0) * 64;
    const u16* kp = kb + (size_t)bh*65536 + (size_t)jt0*4096;
    const u16* vp = vT + (size_t)bh*65536;
    const u16* bp = bias_t + (((size_t)(bh*32 + it*2 + (w>>1)))*16 + jt0)*2048 + ((w&1)*64 + lane)*16;

    if (tid < 128) ((float4*)mjs)[tid] = ((const float4*)(seq_mask + b*1024 + jh*512))[tid];

    bf16x8 aq0 = *(const bf16x8*)&qp[(w*16 + li)*64 + g*8];
    bf16x8 aq1 = *(const bf16x8*)&qp[(w*16 + li)*64 + 32 + g*8];

    const int sli = tid & 15, sg = (tid >> 4) & 3, sf = tid >> 6;
    const int kslot0 = (sf*128 + sg*16 + sli) * 8;
    bf16x8 kr0, kr1, vr0, vr1, bfA_c, bfB_c, bfA_n, bfB_n;
    #define LOADT(jx) do { \
        kr0 = *(const bf16x8*)&kp[(size_t)(jx)*4096 + (sf*16 + sli)*64 + sg*8]; \
        kr1 = *(const bf16x8*)&kp[(size_t)(jx)*4096 + (sf*16 + sli)*64 + 32 + sg*8]; \
        vr0 = *(const bf16x8*)&vp[(size_t)(sf*16 + sli)*1024 + (jt0+(jx))*64 + sg*8]; \
        vr1 = *(const bf16x8*)&vp[(size_t)(sf*16 + sli)*1024 + (jt0+(jx))*64 + 32 + sg*8]; \
        bfA_n = *(const bf16x8*)&bp[(size_t)(jx)*2048]; \
        bfB_n = *(const bf16x8*)&bp[(size_t)(jx)*2048 + 8]; \
    } while (0)
    #define STORET(buf_) do { \
        *(bf16x8*)&Ks[buf_][kslot0]       = kr0; \
        *(bf16x8*)&Ks[buf_][kslot0 + 512] = kr1; \
        *(bf16x8*)&Vs[buf_][kslot0]       = vr0; \
        *(bf16x8*)&Vs[buf_][kslot0 + 512] = vr1; \
    } while (0)

    f32x4 oacc[4] = {};
    float m_run[4], l_run[4], mi[4];
    #pragma unroll
    for (int r = 0; r < 4; r++) {
        m_run[r] = -3e38f; l_run[r] = 0.f;
        mi[r] = seq_mask[b*1024 + i0 + w*16 + g*4 + r];
    }

    LOADT(0); STORET(0); bfA_c = bfA_n; bfB_c = bfB_n;
    __syncthreads();

    for (int jtt = 0; jtt < 8; jtt++) {
        int cur = jtt & 1;
        if (jtt < 7) LOADT(jtt + 1);
        f32x4 s[4] = {};
        #pragma unroll
        for (int fj = 0; fj < 4; fj++) {
            bf16x8 bk0 = *(const bf16x8*)&Ks[cur][(fj*128 + g*16 + li)*8];
            bf16x8 bk1 = *(const bf16x8*)&Ks[cur][(fj*128 + g*16 + li)*8 + 512];
            s[fj] = __builtin_amdgcn_mfma_f32_16x16x32_bf16(aq0, bk0, s[fj], 0, 0, 0);
            s[fj] = __builtin_amdgcn_mfma_f32_16x16x32_bf16(aq1, bk1, s[fj], 0, 0, 0);
        }
        float pmax[4] = {-3e38f, -3e38f, -3e38f, -3e38f};
        #pragma unroll
        for (int fj = 0; fj < 4; fj++) {
            float mj = mjs[jtt*64 + fj*16 + li];
            #pragma unroll
            for (int r = 0; r < 4; r++) {
                float bvl = (r < 2) ? b2f(((u16x8)bfA_c)[r*4 + fj]) : b2f(((u16x8)bfB_c)[(r-2)*4 + fj]);
                float sv = s[fj][r] + bvl;
                sv -= (1.f - mi[r]*mj) * 1e6f;
                s[fj][r] = sv;
                pmax[r] = fmaxf(pmax[r], sv);
            }
        }
        #pragma unroll
        for (int r = 0; r < 4; r++)
            #pragma unroll
            for (int off = 1; off < 16; off <<= 1)
                pmax[r] = fmaxf(pmax[r], __shfl_xor(pmax[r], off));
        float alpha[4], psum[4] = {0.f, 0.f, 0.f, 0.f}, mnew[4];
        #pragma unroll
        for (int r = 0; r < 4; r++) {
            mnew[r] = fmaxf(m_run[r], pmax[r]);
            alpha[r] = __expf(m_run[r] - mnew[r]);
            m_run[r] = mnew[r];
        }
        #pragma unroll
        for (int fj = 0; fj < 4; fj++)
            #pragma unroll
            for (int r = 0; r < 4; r++) {
                float p = __expf(s[fj][r] - mnew[r]);
                s[fj][r] = p;
                psum[r] += p;
            }
        #pragma unroll
        for (int r = 0; r < 4; r++) {
            #pragma unroll
            for (int off = 1; off < 16; off <<= 1) psum[r] += __shfl_xor(psum[r], off);
            l_run[r] = l_run[r]*alpha[r] + psum[r];
        }
        #pragma unroll
        for (int fj = 0; fj < 4; fj++) {
            int ph2 = fj >> 1;
            int pg = (fj*2 + (li >> 3)) & 3;
            int pin = li & 7;
            #pragma unroll
            for (int r = 0; r < 4; r++)
                Ps[w][(ph2*64 + pg*16 + g*4 + r)*8 + pin] = f2b(s[fj][r]);
        }
        #pragma unroll
        for (int fd = 0; fd < 4; fd++)
            #pragma unroll
            for (int r = 0; r < 4; r++)
                oacc[fd][r] *= alpha[r];
        bf16x8 ap0 = *(const bf16x8*)&Ps[w][(g*16 + li)*8];
        bf16x8 ap1 = *(const bf16x8*)&Ps[w][(g*16 + li)*8 + 512];
        #pragma unroll
        for (int fd = 0; fd < 4; fd++) {
            bf16x8 bv0 = *(const bf16x8*)&Vs[cur][(fd*128 + g*16 + li)*8];
            bf16x8 bv1 = *(const bf16x8*)&Vs[cur][(fd*128 + g*16 + li)*8 + 512];
            oacc[fd] = __builtin_amdgcn_mfma_f32_16x16x32_bf16(ap0, bv0, oacc[fd], 0, 0, 0);
            oacc[fd] = __builtin_amdgcn_mfma_f32_16x16x32_bf16(ap1, bv1, oacc[fd], 0, 0, 0);
        }
        if (jtt < 7) { STORET(cur ^ 1); bfA_c = bfA_n; bfB_c = bfB_n; }
        __syncthreads();
    }
    size_t pbase = ((size_t)(bh*16 + it)*2 + jh) * 4096;
    #pragma unroll
    for (int fd = 0; fd < 4; fd++)
        #pragma unroll
        for (int r = 0; r < 4; r++)
            Om[pbase + (size_t)(w*16 + g*4 + r)*64 + fd*16 + li] = oacc[fd][r];
    if (li == 0) {
        #pragma unroll
        for (int r = 0; r < 4; r++) {
            size_t mb = ((size_t)(bh*16 + it)*2 + jh) * 128 + (w*16 + g*4 + r)*2;
            ml[mb] = m_run[r]; ml[mb + 1] = l_run[r];
        }
    }
    #undef LOADT
    #undef STORET
}

// ---------------- kernel 5: merge j-split partials -> aout bf16
__global__ __launch_bounds__(256) void merge_kernel(
    const float* __restrict__ Om, const float* __restrict__ ml, u16* __restrict__ aout)
{
    int blk = blockIdx.x;        // 256: bh*16 + it
    int bh = blk >> 4, it = blk & 15;
    int b = bh >> 3, h = bh & 7;
    int tid = threadIdx.x;
    int row = tid >> 2, dc = (tid & 3) * 16;
    size_t p0 = ((size_t)blk*2 + 0)*4096 + (size_t)row*64 + dc;
    size_t p1 = ((size_t)blk*2 + 1)*4096 + (size_t)row*64 + dc;
    size_t m0i = ((size_t)blk*2 + 0)*128 + row*2;
    size_t m1i = ((size_t)blk*2 + 1)*128 + row*2;
    float m0 = ml[m0i], l0 = ml[m0i + 1];
    float m1 = ml[m1i], l1 = ml[m1i + 1];
    float mm = fmaxf(m0, m1);
    float e0 = __expf(m0 - mm), e1 = __expf(m1 - mm);
    float linv = 1.f / (l0*e0 + l1*e1);
    int i = it*64 + row;
    u16* op = &aout[((size_t)(b*1024 + i))*512 + h*64 + dc];
    #pragma unroll
    for (int c4 = 0; c4 < 4; c4++) {
        f32x4 v0 = *(const f32x4*)&Om[p0 + c4*4];
        f32x4 v1 = *(const f32x4*)&Om[p1 + c4*4];
        ushort4 o;
        o.x = f2b((v0[0]*e0 + v1[0]*e1)*linv);
        o.y = f2b((v0[1]*e0 + v1[1]*e1)*linv);
        o.z = f2b((v0[2]*e0 + v1[2]*e1)*linv);
        o.w = f2b((v0[3]*e0 + v1[3]*e1)*linv);
        *(ushort4*)&op[c4*4] = o;
    }
}

// ---------------- kernel 6: out = attn_out @ Wo^T  (M=2048,K=512,N=512), * mask, f32
__global__ __launch_bounds__(256) void out_gemm_kernel(
    const u16* __restrict__ aout, const u16* __restrict__ wo,
    const float* __restrict__ seq_mask, float* __restrict__ out)
{
    __shared__ u16 As[64][40];
    __shared__ u16 Bs[64][40];
    const int tid = threadIdx.x;
    const int lane = tid & 63, wid = tid >> 6;
    const int wr = wid >> 1, wc = wid & 1;
    const int li = lane & 15, g = lane >> 4;
    const int m0 = blockIdx.x * 64, n0 = blockIdx.y * 64;

    f32x4 acc[2][2] = {};
    const int lrow = tid >> 2, lcol = (tid & 3) * 8;
    for (int k0 = 0; k0 < 512; k0 += 32) {
        *(bf16x8*)&As[lrow][lcol] = *(const bf16x8*)&aout[(size_t)(m0+lrow)*512 + k0 + lcol];
        *(bf16x8*)&Bs[lrow][lcol] = *(const bf16x8*)&wo[(size_t)(n0+lrow)*512 + k0 + lcol];
        __syncthreads();
        bf16x8 a[2], bf[2];
        #pragma unroll
        for (int fi = 0; fi < 2; fi++) a[fi]  = *(const bf16x8*)&As[wr*32 + fi*16 + li][g*8];
        #pragma unroll
        for (int fj = 0; fj < 2; fj++) bf[fj] = *(const bf16x8*)&Bs[wc*32 + fj*16 + li][g*8];
        #pragma unroll
        for (int fi = 0; fi < 2; fi++)
            #pragma unroll
            for (int fj = 0; fj < 2; fj++)
                acc[fi][fj] = __builtin_amdgcn_mfma_f32_16x16x32_bf16(a[fi], bf[fj], acc[fi][fj], 0, 0, 0);
        __syncthreads();
    }
    #pragma unroll
    for (int fi = 0; fi < 2; fi++)
        #pragma unroll
        for (int fj = 0; fj < 2; fj++)
            #pragma unroll
            for (int r = 0; r < 4; r++) {
                int m = m0 + wr*32 + fi*16 + g*4 + r;
                int o = n0 + wc*32 + fj*16 + li;
                out[(size_t)m*512 + o] = acc[fi][fj][r] * seq_mask[m];
            }
}

extern "C" void kernel_launch(void* const* d_in, const int* in_sizes, int n_in,
                              void* d_out, int out_size, void* d_ws, size_t ws_size,
                              hipStream_t stream) {
    const float* x         = (const float*)d_in[0];
    const float* timep     = (const float*)d_in[2];
    const float* attn_bias = (const float*)d_in[3];
    const float* seq_mask  = (const float*)d_in[4];
    const float* gamma     = (const float*)d_in[5];
    const float* Wt        = (const float*)d_in[6];
    const float* bt        = (const float*)d_in[7];
    const float* Wb        = (const float*)d_in[8];
    const float* bb        = (const float*)d_in[9];
    const float* Wq        = (const float*)d_in[10];
    const float* Wkv       = (const float*)d_in[11];
    const float* Wo        = (const float*)d_in[12];
    float* out = (float*)d_out;

    char* ws = (char*)d_ws;
    size_t off = 0;
    auto alloc = [&](size_t bytes) { char* p = ws + off; off += (bytes + 255) & ~(size_t)255; return p; };
    float* tbuf  = (float*)alloc(2 * 1024 * 4);
    u16* xn      = (u16*)alloc((size_t)2048 * 512 * 2);
    u16* wqkv    = (u16*)alloc((size_t)1536 * 512 * 2);
    u16* wo      = (u16*)alloc((size_t)512 * 512 * 2);
    u16* qb      = (u16*)alloc((size_t)2 * 8 * 1024 * 64 * 2);
    u16* kb      = (u16*)alloc((size_t)2 * 8 * 1024 * 64 * 2);
    u16* vT      = (u16*)alloc((size_t)2 * 8 * 64 * 1024 * 2);
    u16* bias_t  = (u16*)alloc((size_t)2 * 8 * 1024 * 1024 * 2);
    u16* aout    = (u16*)alloc((size_t)2048 * 512 * 2);
    float* Om    = (float*)alloc((size_t)256 * 2 * 4096 * 4);
    float* ml    = (float*)alloc((size_t)256 * 2 * 128 * 4);
    (void)ws_size;

    prep_kernel<<<1032, 256, 0, stream>>>(Wq, Wkv, Wo, timep, Wt, bt, wqkv, wo, tbuf);
    ln_cond_kernel<<<2048, 64, 0, stream>>>(x, gamma, tbuf, seq_mask, xn);
    qkv_bias_kernel<<<2816, 256, 0, stream>>>(attn_bias, Wb, bb, xn, wqkv, bias_t, qb, kb, vT);
    attn_kernel<<<dim3(16, 8, 4), 256, 0, stream>>>(qb, kb, vT, bias_t, seq_mask, Om, ml);
    merge_kernel<<<256, 256, 0, stream>>>(Om, ml, aout);
    out_gemm_kernel<<<dim3(32, 8), 256, 0, stream>>>(aout, wo, seq_mask, out);
}

// Round 19
// 86.456 us; speedup vs baseline: 1.0501x; 1.0501x over previous
//
#include <hip/hip_runtime.h>
#include <cstdint>
#include <cstddef>

typedef __bf16 bf16x8 __attribute__((ext_vector_type(8)));
typedef float f32x4 __attribute__((ext_vector_type(4)));
typedef unsigned int u32x4 __attribute__((ext_vector_type(4)));
typedef unsigned short u16;
typedef unsigned short u16x8 __attribute__((ext_vector_type(8)));

__device__ __forceinline__ u16 f2b(float f) {
    union { float f; uint32_t u; } v; v.f = f;
    uint32_t r = v.u + 0x7fffu + ((v.u >> 16) & 1u);
    return (u16)(r >> 16);
}
__device__ __forceinline__ float b2f(u16 h) {
    union { uint32_t u; float f; } v; v.u = ((uint32_t)h) << 16; return v.f;
}

// ---------------- kernel 1: prep = weight bf16 converts + time conditioning
__global__ __launch_bounds__(256) void prep_kernel(
    const float* __restrict__ Wq, const float* __restrict__ Wkv, const float* __restrict__ Wo,
    const float* __restrict__ timep, const float* __restrict__ Wt, const float* __restrict__ bt,
    u16* __restrict__ wqkv, u16* __restrict__ wo, float* __restrict__ tbuf)
{
    __shared__ float st[512];
    int bx = blockIdx.x, tid = threadIdx.x;
    if (bx < 1024) {
        int i = bx * 256 + tid;
        float4 v; u16* dp;
        if (i < 65536)      { v = ((const float4*)Wq)[i];            dp = wqkv + (size_t)i * 4; }
        else if (i < 196608){ int k = i - 65536;  v = ((const float4*)Wkv)[k]; dp = wqkv + 262144 + (size_t)k * 4; }
        else                { int k = i - 196608; v = ((const float4*)Wo)[k];  dp = wo + (size_t)k * 4; }
        ushort4 o;
        o.x = f2b(v.x); o.y = f2b(v.y); o.z = f2b(v.z); o.w = f2b(v.w);
        *(ushort4*)dp = o;
    } else {
        int bx2 = bx - 1024;          // 8 blocks
        int b = bx2 >> 2, ch = bx2 & 3;
        for (int k = tid; k < 512; k += 256) {
            float v = timep[b * 512 + k];
            st[k] = v / (1.f + __expf(-v));
        }
        __syncthreads();
        int o = ch * 256 + tid;
        const float4* wrow = (const float4*)(Wt + (size_t)o * 512);
        float acc = bt[o];
        #pragma unroll 4
        for (int k4 = 0; k4 < 128; k4++) {
            float4 w = wrow[k4];
            acc += st[k4*4+0]*w.x + st[k4*4+1]*w.y + st[k4*4+2]*w.z + st[k4*4+3]*w.w;
        }
        tbuf[b * 1024 + o] = acc;
    }
}

// ---------------- kernel 2: LayerNorm + (scale+1)*x + shift, * mask -> xn bf16
__global__ __launch_bounds__(64) void ln_cond_kernel(
    const float* __restrict__ x, const float* __restrict__ gamma,
    const float* __restrict__ tbuf, const float* __restrict__ seq_mask,
    u16* __restrict__ xn)
{
    int m = blockIdx.x;              // 0..2047  (b*1024+n)
    int b = m >> 10;
    int lane = threadIdx.x;
    const float* xr = x + (size_t)m * 512;
    int c0 = lane * 8;
    float4 v0 = *(const float4*)(xr + c0);
    float4 v1 = *(const float4*)(xr + c0 + 4);
    float xv[8] = {v0.x, v0.y, v0.z, v0.w, v1.x, v1.y, v1.z, v1.w};
    float s = 0.f, ss = 0.f;
    #pragma unroll
    for (int e = 0; e < 8; e++) { s += xv[e]; ss += xv[e]*xv[e]; }
    #pragma unroll
    for (int off = 1; off < 64; off <<= 1) {
        s  += __shfl_xor(s, off);
        ss += __shfl_xor(ss, off);
    }
    float mu = s * (1.f/512.f);
    float var = ss * (1.f/512.f) - mu*mu;
    float rs = rsqrtf(var + 1e-5f);
    float mk = seq_mask[m];
    u16x8 ov;
    #pragma unroll
    for (int e = 0; e < 8; e++) {
        int c = c0 + e;
        float sc = tbuf[b*1024 + c] + 1.f;
        float sh = tbuf[b*1024 + 512 + c];
        float val = ((xv[e] - mu) * rs * gamma[c] * sc + sh) * mk;
        ov[e] = f2b(val);
    }
    *(u16x8*)&xn[(size_t)m * 512 + c0] = ov;
}

// ---------------- kernel 3: fused [QKV GEMM 64^2 (blocks 0..767)] + [bias (768..2815)]
// __launch_bounds__(256,8) caps VGPR at 64 -> bias blocks get probe-level occupancy.
// bias_t frag layout per 64x64 tile: [slot = isub*64 + g*16 + li][r*4 + fj]
#define TST 68
__global__ __launch_bounds__(256, 8) void qkv_bias_kernel(
    const float* __restrict__ ab, const float* __restrict__ Wb, const float* __restrict__ bbv,
    const u16* __restrict__ xn, const u16* __restrict__ wqkv,
    u16* __restrict__ bias_t, u16* __restrict__ qb, u16* __restrict__ kb, u16* __restrict__ vT)
{
    __shared__ u16 SH[8704];         // bias: Ts[8*16*68]=17408B; GEMM: As[64][40]+Bs[64][40]=10240B
    __shared__ float wbs[128];
    __shared__ float bbs[8];
    const int tid = threadIdx.x;
    const int bx = blockIdx.x;
    if (bx >= 768) {
        // ---- bias path (probe-profile) ----
        if (tid < 128) wbs[tid] = Wb[tid];
        if (tid < 8) bbs[tid] = bbv[tid];
        __syncthreads();
        int bx2 = bx - 768;             // 0..2047
        int b = bx2 >> 10;
        int rem = bx2 & 1023;
        int i16 = rem >> 4;             // 16-row group
        int jt  = rem & 15;
        int il = tid >> 4, jq = tid & 15;
        int i = i16*16 + il;
        int j = jt*64 + jq*4;
        const float* base = ab + (((size_t)b << 24)) + ((size_t)i << 10) + j;

        int a0 = bx2 & 15;              // staggered plane start (channel spread)
        f32x4 acc[8];
        #pragma unroll
        for (int h = 0; h < 8; h++) {
            float bv = bbs[h];
            acc[h][0] = bv; acc[h][1] = bv; acc[h][2] = bv; acc[h][3] = bv;
        }
        f32x4 v[16];
        #pragma unroll
        for (int k = 0; k < 16; k++) {
            int a = (a0 + k) & 15;
            v[k] = *(const f32x4*)(base + ((size_t)a << 20));
        }
        #pragma unroll
        for (int k = 0; k < 16; k++) {
            int a = (a0 + k) & 15;
            #pragma unroll
            for (int h = 0; h < 8; h++)
                acc[h] += wbs[h*16 + a] * v[k];
        }
        // to LDS (bf16), layout [h][il][j-local], stride TST
        #pragma unroll
        for (int h = 0; h < 8; h++) {
            ushort4 o;
            o.x = f2b(acc[h][0]); o.y = f2b(acc[h][1]); o.z = f2b(acc[h][2]); o.w = f2b(acc[h][3]);
            *(ushort4*)&SH[(h*16 + il)*TST + jq*4] = o;
        }
        __syncthreads();
        // frag-order read + contiguous store
        int hh = tid >> 5;
        int s0 = tid & 31;
        size_t tilebase = ((((size_t)(b*8 + hh))*32 + (i16 >> 1))*16 + jt)*2048 + (size_t)(i16 & 1)*1024;
        #pragma unroll
        for (int ss = 0; ss < 2; ss++) {
            int slot = s0 + ss*32;
            int g = slot >> 4, li = slot & 15;
            u16 tmp[16];
            #pragma unroll
            for (int r = 0; r < 4; r++)
                #pragma unroll
                for (int fj = 0; fj < 4; fj++)
                    tmp[r*4 + fj] = SH[(hh*16 + g*4 + r)*TST + fj*16 + li];
            *(uint4*)&bias_t[tilebase + (size_t)slot*16]     = *(uint4*)&tmp[0];
            *(uint4*)&bias_t[tilebase + (size_t)slot*16 + 8] = *(uint4*)&tmp[8];
        }
    } else {
        // ---- qkv GEMM path, 64x64 tile (low VGPR), dispatched first ----
        u16 (*As)[40] = (u16(*)[40])&SH[0];
        u16 (*Bs)[40] = (u16(*)[40])&SH[2560];
        int v = bx;                  // 0..767: 32 m-tiles x 24 n-tiles
        const int m0 = (v & 31) * 64, n0 = (v >> 5) * 64;
        const int lane = tid & 63, wid = tid >> 6;
        const int wr = wid >> 1, wc = wid & 1;
        const int li = lane & 15, g = lane >> 4;
        f32x4 acc[2][2] = {};
        const int lrow = tid >> 2, lcol = (tid & 3) * 8;
        for (int k0 = 0; k0 < 512; k0 += 32) {
            *(bf16x8*)&As[lrow][lcol] = *(const bf16x8*)&xn[(size_t)(m0+lrow)*512 + k0 + lcol];
            *(bf16x8*)&Bs[lrow][lcol] = *(const bf16x8*)&wqkv[(size_t)(n0+lrow)*512 + k0 + lcol];
            __syncthreads();
            bf16x8 a[2], bf[2];
            #pragma unroll
            for (int fi = 0; fi < 2; fi++) a[fi]  = *(const bf16x8*)&As[wr*32 + fi*16 + li][g*8];
            #pragma unroll
            for (int fj = 0; fj < 2; fj++) bf[fj] = *(const bf16x8*)&Bs[wc*32 + fj*16 + li][g*8];
            #pragma unroll
            for (int fi = 0; fi < 2; fi++)
                #pragma unroll
                for (int fj = 0; fj < 2; fj++)
                    acc[fi][fj] = __builtin_amdgcn_mfma_f32_16x16x32_bf16(a[fi], bf[fj], acc[fi][fj], 0, 0, 0);
            __syncthreads();
        }
        #pragma unroll
        for (int fi = 0; fi < 2; fi++)
            #pragma unroll
            for (int fj = 0; fj < 2; fj++) {
                int o = n0 + wc*32 + fj*16 + li;
                int m_base = m0 + wr*32 + fi*16 + g*4;
                if (o < 1024) {
                    #pragma unroll
                    for (int r = 0; r < 4; r++) {
                        int m = m_base + r;
                        int b = m >> 10, n = m & 1023;
                        float vv = acc[fi][fj][r];
                        if (o < 512) {
                            qb[((size_t)(b*8 + (o>>6))*1024 + n)*64 + (o&63)] = f2b(vv * 0.125f);
                        } else {
                            int oo = o - 512;
                            kb[((size_t)(b*8 + (oo>>6))*1024 + n)*64 + (oo&63)] = f2b(vv);
                        }
                    }
                } else {
                    int oo = o - 1024;
                    int b = m_base >> 10, n = m_base & 1023;
                    ushort4 ov;
                    ov.x = f2b(acc[fi][fj][0]); ov.y = f2b(acc[fi][fj][1]);
                    ov.z = f2b(acc[fi][fj][2]); ov.w = f2b(acc[fi][fj][3]);
                    *(ushort4*)&vT[((size_t)(b*8 + (oo>>6))*64 + (oo&63))*1024 + n] = ov;
                }
            }
    }
}

// ---------------- kernel 4: flash attention, lane-linear LDS slots, j-split x2 (R8 exact)
__global__ __launch_bounds__(256) void attn_kernel(
    const u16* __restrict__ qb, const u16* __restrict__ kb, const u16* __restrict__ vT,
    const u16* __restrict__ bias_t, const float* __restrict__ seq_mask,
    float* __restrict__ Om, float* __restrict__ ml)
{
    __shared__ u16 Ks[2][4096];
    __shared__ u16 Vs[2][4096];
    __shared__ u16 Ps[4][1024];
    __shared__ float mjs[512];
    int tid = threadIdx.x;
    int lane = tid & 63, w = tid >> 6;
    int li = lane & 15, g = lane >> 4;
    int it = blockIdx.x, h = blockIdx.y;
    int bz = blockIdx.z;
    int b = bz >> 1, jh = bz & 1;
    int bh = b*8 + h;
    int i0 = it * 64;
    int jt0 = jh * 8;
    const u16* qp = qb + ((size_t)bh*1024 + i0) * 64;
    const u16* kp = kb + (size_t)bh*65536 + (size_t)jt0*4096;
    const u16* vp = vT + (size_t)bh*65536;
    const u16* bp = bias_t + (((size_t)(bh*32 + it*2 + (w>>1)))*16 + jt0)*2048 + ((w&1)*64 + lane)*16;

    if (tid < 128) ((float4*)mjs)[tid] = ((const float4*)(seq_mask + b*1024 + jh*512))[tid];

    bf16x8 aq0 = *(const bf16x8*)&qp[(w*16 + li)*64 + g*8];
    bf16x8 aq1 = *(const bf16x8*)&qp[(w*16 + li)*64 + 32 + g*8];

    const int sli = tid & 15, sg = (tid >> 4) & 3, sf = tid >> 6;
    const int kslot0 = (sf*128 + sg*16 + sli) * 8;
    bf16x8 kr0, kr1, vr0, vr1, bfA_c, bfB_c, bfA_n, bfB_n;
    #define LOADT(jx) do { \
        kr0 = *(const bf16x8*)&kp[(size_t)(jx)*4096 + (sf*16 + sli)*64 + sg*8]; \
        kr1 = *(const bf16x8*)&kp[(size_t)(jx)*4096 + (sf*16 + sli)*64 + 32 + sg*8]; \
        vr0 = *(const bf16x8*)&vp[(size_t)(sf*16 + sli)*1024 + (jt0+(jx))*64 + sg*8]; \
        vr1 = *(const bf16x8*)&vp[(size_t)(sf*16 + sli)*1024 + (jt0+(jx))*64 + 32 + sg*8]; \
        bfA_n = *(const bf16x8*)&bp[(size_t)(jx)*2048]; \
        bfB_n = *(const bf16x8*)&bp[(size_t)(jx)*2048 + 8]; \
    } while (0)
    #define STORET(buf_) do { \
        *(bf16x8*)&Ks[buf_][kslot0]       = kr0; \
        *(bf16x8*)&Ks[buf_][kslot0 + 512] = kr1; \
        *(bf16x8*)&Vs[buf_][kslot0]       = vr0; \
        *(bf16x8*)&Vs[buf_][kslot0 + 512] = vr1; \
    } while (0)

    f32x4 oacc[4] = {};
    float m_run[4], l_run[4], mi[4];
    #pragma unroll
    for (int r = 0; r < 4; r++) {
        m_run[r] = -3e38f; l_run[r] = 0.f;
        mi[r] = seq_mask[b*1024 + i0 + w*16 + g*4 + r];
    }

    LOADT(0); STORET(0); bfA_c = bfA_n; bfB_c = bfB_n;
    __syncthreads();

    for (int jtt = 0; jtt < 8; jtt++) {
        int cur = jtt & 1;
        if (jtt < 7) LOADT(jtt + 1);
        f32x4 s[4] = {};
        #pragma unroll
        for (int fj = 0; fj < 4; fj++) {
            bf16x8 bk0 = *(const bf16x8*)&Ks[cur][(fj*128 + g*16 + li)*8];
            bf16x8 bk1 = *(const bf16x8*)&Ks[cur][(fj*128 + g*16 + li)*8 + 512];
            s[fj] = __builtin_amdgcn_mfma_f32_16x16x32_bf16(aq0, bk0, s[fj], 0, 0, 0);
            s[fj] = __builtin_amdgcn_mfma_f32_16x16x32_bf16(aq1, bk1, s[fj], 0, 0, 0);
        }
        float pmax[4] = {-3e38f, -3e38f, -3e38f, -3e38f};
        #pragma unroll
        for (int fj = 0; fj < 4; fj++) {
            float mj = mjs[jtt*64 + fj*16 + li];
            #pragma unroll
            for (int r = 0; r < 4; r++) {
                float bvl = (r < 2) ? b2f(((u16x8)bfA_c)[r*4 + fj]) : b2f(((u16x8)bfB_c)[(r-2)*4 + fj]);
                float sv = s[fj][r] + bvl;
                sv -= (1.f - mi[r]*mj) * 1e6f;
                s[fj][r] = sv;
                pmax[r] = fmaxf(pmax[r], sv);
            }
        }
        #pragma unroll
        for (int r = 0; r < 4; r++)
            #pragma unroll
            for (int off = 1; off < 16; off <<= 1)
                pmax[r] = fmaxf(pmax[r], __shfl_xor(pmax[r], off));
        float alpha[4], psum[4] = {0.f, 0.f, 0.f, 0.f}, mnew[4];
        #pragma unroll
        for (int r = 0; r < 4; r++) {
            mnew[r] = fmaxf(m_run[r], pmax[r]);
            alpha[r] = __expf(m_run[r] - mnew[r]);
            m_run[r] = mnew[r];
        }
        #pragma unroll
        for (int fj = 0; fj < 4; fj++)
            #pragma unroll
            for (int r = 0; r < 4; r++) {
                float p = __expf(s[fj][r] - mnew[r]);
                s[fj][r] = p;
                psum[r] += p;
            }
        #pragma unroll
        for (int r = 0; r < 4; r++) {
            #pragma unroll
            for (int off = 1; off < 16; off <<= 1) psum[r] += __shfl_xor(psum[r], off);
            l_run[r] = l_run[r]*alpha[r] + psum[r];
        }
        #pragma unroll
        for (int fj = 0; fj < 4; fj++) {
            int ph2 = fj >> 1;
            int pg = (fj*2 + (li >> 3)) & 3;
            int pin = li & 7;
            #pragma unroll
            for (int r = 0; r < 4; r++)
                Ps[w][(ph2*64 + pg*16 + g*4 + r)*8 + pin] = f2b(s[fj][r]);
        }
        #pragma unroll
        for (int fd = 0; fd < 4; fd++)
            #pragma unroll
            for (int r = 0; r < 4; r++)
                oacc[fd][r] *= alpha[r];
        bf16x8 ap0 = *(const bf16x8*)&Ps[w][(g*16 + li)*8];
        bf16x8 ap1 = *(const bf16x8*)&Ps[w][(g*16 + li)*8 + 512];
        #pragma unroll
        for (int fd = 0; fd < 4; fd++) {
            bf16x8 bv0 = *(const bf16x8*)&Vs[cur][(fd*128 + g*16 + li)*8];
            bf16x8 bv1 = *(const bf16x8*)&Vs[cur][(fd*128 + g*16 + li)*8 + 512];
            oacc[fd] = __builtin_amdgcn_mfma_f32_16x16x32_bf16(ap0, bv0, oacc[fd], 0, 0, 0);
            oacc[fd] = __builtin_amdgcn_mfma_f32_16x16x32_bf16(ap1, bv1, oacc[fd], 0, 0, 0);
        }
        if (jtt < 7) { STORET(cur ^ 1); bfA_c = bfA_n; bfB_c = bfB_n; }
        __syncthreads();
    }
    size_t pbase = ((size_t)(bh*16 + it)*2 + jh) * 4096;
    #pragma unroll
    for (int fd = 0; fd < 4; fd++)
        #pragma unroll
        for (int r = 0; r < 4; r++)
            Om[pbase + (size_t)(w*16 + g*4 + r)*64 + fd*16 + li] = oacc[fd][r];
    if (li == 0) {
        #pragma unroll
        for (int r = 0; r < 4; r++) {
            size_t mb = ((size_t)(bh*16 + it)*2 + jh) * 128 + (w*16 + g*4 + r)*2;
            ml[mb] = m_run[r]; ml[mb + 1] = l_run[r];
        }
    }
    #undef LOADT
    #undef STORET
}

// ---------------- kernel 5: merge j-split partials -> aout bf16
__global__ __launch_bounds__(256) void merge_kernel(
    const float* __restrict__ Om, const float* __restrict__ ml, u16* __restrict__ aout)
{
    int blk = blockIdx.x;        // 256: bh*16 + it
    int bh = blk >> 4, it = blk & 15;
    int b = bh >> 3, h = bh & 7;
    int tid = threadIdx.x;
    int row = tid >> 2, dc = (tid & 3) * 16;
    size_t p0 = ((size_t)blk*2 + 0)*4096 + (size_t)row*64 + dc;
    size_t p1 = ((size_t)blk*2 + 1)*4096 + (size_t)row*64 + dc;
    size_t m0i = ((size_t)blk*2 + 0)*128 + row*2;
    size_t m1i = ((size_t)blk*2 + 1)*128 + row*2;
    float m0 = ml[m0i], l0 = ml[m0i + 1];
    float m1 = ml[m1i], l1 = ml[m1i + 1];
    float mm = fmaxf(m0, m1);
    float e0 = __expf(m0 - mm), e1 = __expf(m1 - mm);
    float linv = 1.f / (l0*e0 + l1*e1);
    int i = it*64 + row;
    u16* op = &aout[((size_t)(b*1024 + i))*512 + h*64 + dc];
    #pragma unroll
    for (int c4 = 0; c4 < 4; c4++) {
        f32x4 v0 = *(const f32x4*)&Om[p0 + c4*4];
        f32x4 v1 = *(const f32x4*)&Om[p1 + c4*4];
        ushort4 o;
        o.x = f2b((v0[0]*e0 + v1[0]*e1)*linv);
        o.y = f2b((v0[1]*e0 + v1[1]*e1)*linv);
        o.z = f2b((v0[2]*e0 + v1[2]*e1)*linv);
        o.w = f2b((v0[3]*e0 + v1[3]*e1)*linv);
        *(ushort4*)&op[c4*4] = o;
    }
}

// ---------------- kernel 6: out = attn_out @ Wo^T  (M=2048,K=512,N=512), * mask, f32
__global__ __launch_bounds__(256) void out_gemm_kernel(
    const u16* __restrict__ aout, const u16* __restrict__ wo,
    const float* __restrict__ seq_mask, float* __restrict__ out)
{
    __shared__ u16 As[64][40];
    __shared__ u16 Bs[64][40];
    const int tid = threadIdx.x;
    const int lane = tid & 63, wid = tid >> 6;
    const int wr = wid >> 1, wc = wid & 1;
    const int li = lane & 15, g = lane >> 4;
    const int m0 = blockIdx.x * 64, n0 = blockIdx.y * 64;

    f32x4 acc[2][2] = {};
    const int lrow = tid >> 2, lcol = (tid & 3) * 8;
    for (int k0 = 0; k0 < 512; k0 += 32) {
        *(bf16x8*)&As[lrow][lcol] = *(const bf16x8*)&aout[(size_t)(m0+lrow)*512 + k0 + lcol];
        *(bf16x8*)&Bs[lrow][lcol] = *(const bf16x8*)&wo[(size_t)(n0+lrow)*512 + k0 + lcol];
        __syncthreads();
        bf16x8 a[2], bf[2];
        #pragma unroll
        for (int fi = 0; fi < 2; fi++) a[fi]  = *(const bf16x8*)&As[wr*32 + fi*16 + li][g*8];
        #pragma unroll
        for (int fj = 0; fj < 2; fj++) bf[fj] = *(const bf16x8*)&Bs[wc*32 + fj*16 + li][g*8];
        #pragma unroll
        for (int fi = 0; fi < 2; fi++)
            #pragma unroll
            for (int fj = 0; fj < 2; fj++)
                acc[fi][fj] = __builtin_amdgcn_mfma_f32_16x16x32_bf16(a[fi], bf[fj], acc[fi][fj], 0, 0, 0);
        __syncthreads();
    }
    #pragma unroll
    for (int fi = 0; fi < 2; fi++)
        #pragma unroll
        for (int fj = 0; fj < 2; fj++)
            #pragma unroll
            for (int r = 0; r < 4; r++) {
                int m = m0 + wr*32 + fi*16 + g*4 + r;
                int o = n0 + wc*32 + fj*16 + li;
                out[(size_t)m*512 + o] = acc[fi][fj][r] * seq_mask[m];
            }
}

extern "C" void kernel_launch(void* const* d_in, const int* in_sizes, int n_in,
                              void* d_out, int out_size, void* d_ws, size_t ws_size,
                              hipStream_t stream) {
    const float* x         = (const float*)d_in[0];
    const float* timep     = (const float*)d_in[2];
    const float* attn_bias = (const float*)d_in[3];
    const float* seq_mask  = (const float*)d_in[4];
    const float* gamma     = (const float*)d_in[5];
    const float* Wt        = (const float*)d_in[6];
    const float* bt        = (const float*)d_in[7];
    const float* Wb        = (const float*)d_in[8];
    const float* bb        = (const float*)d_in[9];
    const float* Wq        = (const float*)d_in[10];
    const float* Wkv       = (const float*)d_in[11];
    const float* Wo        = (const float*)d_in[12];
    float* out = (float*)d_out;

    char* ws = (char*)d_ws;
    size_t off = 0;
    auto alloc = [&](size_t bytes) { char* p = ws + off; off += (bytes + 255) & ~(size_t)255; return p; };
    float* tbuf  = (float*)alloc(2 * 1024 * 4);
    u16* xn      = (u16*)alloc((size_t)2048 * 512 * 2);
    u16* wqkv    = (u16*)alloc((size_t)1536 * 512 * 2);
    u16* wo      = (u16*)alloc((size_t)512 * 512 * 2);
    u16* qb      = (u16*)alloc((size_t)2 * 8 * 1024 * 64 * 2);
    u16* kb      = (u16*)alloc((size_t)2 * 8 * 1024 * 64 * 2);
    u16* vT      = (u16*)alloc((size_t)2 * 8 * 64 * 1024 * 2);
    u16* bias_t  = (u16*)alloc((size_t)2 * 8 * 1024 * 1024 * 2);
    u16* aout    = (u16*)alloc((size_t)2048 * 512 * 2);
    float* Om    = (float*)alloc((size_t)256 * 2 * 4096 * 4);
    float* ml    = (float*)alloc((size_t)256 * 2 * 128 * 4);
    (void)ws_size;

    prep_kernel<<<1032, 256, 0, stream>>>(Wq, Wkv, Wo, timep, Wt, bt, wqkv, wo, tbuf);
    ln_cond_kernel<<<2048, 64, 0, stream>>>(x, gamma, tbuf, seq_mask, xn);
    qkv_bias_kernel<<<2816, 256, 0, stream>>>(attn_bias, Wb, bb, xn, wqkv, bias_t, qb, kb, vT);
    attn_kernel<<<dim3(16, 8, 4), 256, 0, stream>>>(qb, kb, vT, bias_t, seq_mask, Om, ml);
    merge_kernel<<<256, 256, 0, stream>>>(Om, ml, aout);
    out_gemm_kernel<<<dim3(32, 8), 256, 0, stream>>>(aout, wo, seq_mask, out);
}